// Round 8
// baseline (548.374 us; speedup 1.0000x reference)
//
#include <hip/hip_runtime.h>

using u32 = unsigned int;
using s64 = long long;

// -------- int width detection (int64 iff hi-words of first 64 entries all 0) --------
__global__ __launch_bounds__(64) void k_detect13(const u32* __restrict__ ei,
                                                 const u32* __restrict__ nt,
                                                 const u32* __restrict__ tp,
                                                 u32* __restrict__ flags) {
    if (blockIdx.x != 0 || threadIdx.x != 0) return;
    bool e64 = true, n64 = true, t64 = true;
    for (int k = 0; k < 64; ++k) {
        if (ei[2 * k + 1] != 0u) e64 = false;
        if (nt[2 * k + 1] != 0u) n64 = false;
        if (tp[2 * k + 1] != 0u) t64 = false;
    }
    flags[0] = e64 ? 1u : 0u;
    flags[1] = n64 ? 1u : 0u;
    flags[2] = t64 ? 1u : 0u;
}

// -------- width-adaptive convert to int32 --------
__global__ __launch_bounds__(256) void k_cvt13(const void* __restrict__ src,
                                               int* __restrict__ dst, long long n,
                                               const u32* __restrict__ flags, int fidx) {
    long long i = (long long)blockIdx.x * 256 + threadIdx.x;
    if (i >= n) return;
    dst[i] = flags[fidx] ? (int)((const s64*)src)[i] : ((const int*)src)[i];
}

// ---------------- zero (float / int) ----------------
__global__ __launch_bounds__(256) void kz13(float* __restrict__ p, long long n) {
    long long i = (long long)blockIdx.x * 256 + threadIdx.x;
    if (i < n) p[i] = 0.f;
}
__global__ __launch_bounds__(256) void kz_i(int* __restrict__ p, int n) {
    int i = blockIdx.x * 256 + threadIdx.x;
    if (i < n) p[i] = 0;
}

// ---------------- counting sort of edges by col ----------------
__global__ __launch_bounds__(256) void k_hist(const int* __restrict__ ei, int E,
                                              int* __restrict__ cnt) {
    int e = blockIdx.x * 256 + threadIdx.x;
    if (e < E) atomicAdd(&cnt[ei[E + e]], 1);
}

__global__ __launch_bounds__(1024) void k_scan(const int* __restrict__ cnt,
                                               int* __restrict__ offA, int N) {
    __shared__ int part[1024];
    int t = threadIdx.x;
    int C = (N + 1023) >> 10;
    int beg = t * C, end = beg + C; if (end > N) end = N;
    int s = 0;
    for (int k = beg; k < end; ++k) s += cnt[k];
    part[t] = s; __syncthreads();
    for (int o = 1; o < 1024; o <<= 1) {
        int v = (t >= o) ? part[t - o] : 0;
        __syncthreads();
        part[t] += v;
        __syncthreads();
    }
    int base = (t == 0) ? 0 : part[t - 1];
    for (int k = beg; k < end; ++k) { offA[k] = base; base += cnt[k]; }
    if (t == 1023) offA[N] = part[1023];
}

__global__ __launch_bounds__(256) void k_scatter(const int* __restrict__ ei, int E,
                                                 const int* __restrict__ offA,
                                                 int* __restrict__ cur,
                                                 int* __restrict__ srow,
                                                 int* __restrict__ sedge) {
    int e = blockIdx.x * 256 + threadIdx.x;
    if (e >= E) return;
    int col = ei[E + e];
    int p = offA[col] + atomicAdd(&cur[col], 1);
    srow[p] = ei[e];
    sedge[p] = e;
}

// ---------------- counting sort of nodes by type (6 bins) ----------------
__global__ __launch_bounds__(256) void k_thist(const int* __restrict__ nt, int N,
                                               int* __restrict__ tcnt) {
    __shared__ int lc[6];
    if (threadIdx.x < 6) lc[threadIdx.x] = 0;
    __syncthreads();
    int i = blockIdx.x * 256 + threadIdx.x;
    if (i < N) {
        int t = nt[i]; t = (t < 0 || t > 5) ? 0 : t;
        atomicAdd(&lc[t], 1);
    }
    __syncthreads();
    if (threadIdx.x < 6 && lc[threadIdx.x] > 0) atomicAdd(&tcnt[threadIdx.x], lc[threadIdx.x]);
}

__global__ __launch_bounds__(64) void k_tscan(const int* __restrict__ tcnt,
                                              int* __restrict__ toff) {
    if (threadIdx.x != 0 || blockIdx.x != 0) return;
    int s = 0;
    for (int t = 0; t < 6; ++t) { toff[t] = s; s += tcnt[t]; }
    toff[6] = s;
}

__global__ __launch_bounds__(256) void k_tscatter(const int* __restrict__ nt, int N,
                                                  const int* __restrict__ toff,
                                                  int* __restrict__ tcur,
                                                  int* __restrict__ perm) {
    __shared__ int lc[6], gb[6];
    if (threadIdx.x < 6) lc[threadIdx.x] = 0;
    __syncthreads();
    int i = blockIdx.x * 256 + threadIdx.x;
    int t = 0, lr = 0;
    if (i < N) {
        t = nt[i]; t = (t < 0 || t > 5) ? 0 : t;
        lr = atomicAdd(&lc[t], 1);
    }
    __syncthreads();
    if (threadIdx.x < 6 && lc[threadIdx.x] > 0)
        gb[threadIdx.x] = atomicAdd(&tcur[threadIdx.x], lc[threadIdx.x]);
    __syncthreads();
    if (i < N) perm[toff[t] + gb[t] + lr] = i;
}

__device__ __forceinline__ float2 ld2(const float* p) { return *(const float2*)p; }
__device__ __forceinline__ void st2(float* p, float2 v) { *(float2*)p = v; }
__device__ __forceinline__ float4 ld4(const float* p) { return *(const float4*)p; }
__device__ __forceinline__ void st4(float* p, float4 v) { *(float4*)p = v; }
__device__ __forceinline__ void fma4(float4& a, float s, float4 w) {
    a.x = fmaf(s, w.x, a.x); a.y = fmaf(s, w.y, a.y);
    a.z = fmaf(s, w.z, a.z); a.w = fmaf(s, w.w, a.w);
}

// reduce over the 32-lane tc group (lanes with same tn)
__device__ __forceinline__ float redrow(float s) {
#pragma unroll
    for (int o = 1; o < 32; o <<= 1) s += __shfl_xor(s, o);
    return s;
}

// ======================= pipelined staged matmul =======================
// Block = 256 threads; tile = 32 nodes x 128 cols. LDS: xs 16KB + wl 64KB (full W)
// = 80KB -> 2 blocks/CU. W travels L2 -> regs (prefetched during PREVIOUS matmul's
// compute) -> LDS. 2 barriers per matmul; next-stage xs input stored inside the
// same barrier window.

// preload a full 128x128 W into 16 float4 regs (64 VGPR)
__device__ __forceinline__ void wpre(float4 (&wreg)[16], const float* __restrict__ Wg) {
    int t = threadIdx.x;
#pragma unroll
    for (int i = 0; i < 16; ++i) wreg[i] = ld4(Wg + (size_t)(t + i * 256) * 4);
}

// acc += xs_tile @ W, with W arriving via wreg. Optionally store xin into xs and
// prefetch Wnext into wreg inside the barrier window. ALL 256 threads must call.
__device__ __forceinline__ void mmP(float4 (&acc)[4], float* xs, float* wl,
                                    float4 (&wreg)[16], const float* __restrict__ Wnext,
                                    const float4* xin, int tn, int tc) {
    int t = threadIdx.x;
    __syncthreads();                 // prev wl/xs readers done
#pragma unroll
    for (int i = 0; i < 16; ++i) st4(wl + (size_t)(t + i * 256) * 4, wreg[i]);
    if (xin) {
#pragma unroll
        for (int j = 0; j < 4; ++j) st4(xs + (tn * 4 + j) * 128 + tc * 4, xin[j]);
    }
    if (Wnext) wpre(wreg, Wnext);    // L2 latency hides under the compute below
    __syncthreads();                 // wl + xs visible
#pragma unroll 2
    for (int k4 = 0; k4 < 32; ++k4) {
        float4 w0 = ld4(wl + (k4 * 4 + 0) * 128 + tc * 4);
        float4 w1 = ld4(wl + (k4 * 4 + 1) * 128 + tc * 4);
        float4 w2 = ld4(wl + (k4 * 4 + 2) * 128 + tc * 4);
        float4 w3 = ld4(wl + (k4 * 4 + 3) * 128 + tc * 4);
#pragma unroll
        for (int j = 0; j < 4; ++j) {
            float4 xv = ld4(xs + (tn * 4 + j) * 128 + k4 * 4);
            fma4(acc[j], xv.x, w0); fma4(acc[j], xv.y, w1);
            fma4(acc[j], xv.z, w2); fma4(acc[j], xv.w, w3);
        }
    }
}

// direct-from-L2 matmul (rare boundary blocks only)
__device__ __forceinline__ void mmG(float4 (&acc)[4], const float* xs,
                                    const float* __restrict__ W, int tn, int tc) {
#pragma unroll 2
    for (int k4 = 0; k4 < 32; ++k4) {
        float4 w0 = ld4(W + (size_t)(k4 * 4 + 0) * 128 + tc * 4);
        float4 w1 = ld4(W + (size_t)(k4 * 4 + 1) * 128 + tc * 4);
        float4 w2 = ld4(W + (size_t)(k4 * 4 + 2) * 128 + tc * 4);
        float4 w3 = ld4(W + (size_t)(k4 * 4 + 3) * 128 + tc * 4);
#pragma unroll
        for (int j = 0; j < 4; ++j) {
            float4 xv = ld4(xs + (tn * 4 + j) * 128 + k4 * 4);
            fma4(acc[j], xv.x, w0); fma4(acc[j], xv.y, w1);
            fma4(acc[j], xv.z, w2); fma4(acc[j], xv.w, w3);
        }
    }
}

// LayerNorm of a node row held as float4/lane across 32 tc lanes
__device__ __forceinline__ float4 lnrow(float4 v, const float* g, const float* b, int tc) {
    float m = redrow(v.x + v.y + v.z + v.w) * 0.0078125f;
    float4 d = make_float4(v.x - m, v.y - m, v.z - m, v.w - m);
    float var = redrow(d.x * d.x + d.y * d.y + d.z * d.z + d.w * d.w) * 0.0078125f;
    float r = rsqrtf(var + 1e-5f);
    float4 gg = ld4(g + tc * 4), bb = ld4(b + tc * 4);
    return make_float4(d.x * r * gg.x + bb.x, d.y * r * gg.y + bb.y,
                       d.z * r * gg.z + bb.z, d.w * r * gg.w + bb.w);
}

// stage 32 rows of src (consecutive nodes i0..) into xs; mmP's first sync covers it
__device__ __forceinline__ void stage32(float* xs, const float* src, int i0, int N) {
    int t = threadIdx.x;
#pragma unroll
    for (int ii = 0; ii < 4; ++ii) {
        int idx = t + ii * 256;
        int r = idx >> 5, c = idx & 31;
        int node = i0 + r; if (node >= N) node = N - 1;
        st4(xs + r * 128 + c * 4, ld4(src + (size_t)node * 128 + c * 4));
    }
}

// ---------------- QKV: 3 pipelined matmuls per block ----------------
__global__ __launch_bounds__(256) void k_qkvT(const float* __restrict__ x,
                                              const float* __restrict__ Wq,
                                              const float* __restrict__ Wk,
                                              const float* __restrict__ Wv,
                                              float* __restrict__ big, int N) {
    __shared__ float xs[32 * 128];
    __shared__ float wl[128 * 128];
    int t = threadIdx.x, tn = t >> 5, tc = t & 31;
    int i0 = blockIdx.x * 32;
    stage32(xs, x, i0, N);
    float4 wreg[16];
    wpre(wreg, Wq);
    const float* Ws[3] = {Wq, Wk, Wv};
    float4 acc[4];
#pragma unroll
    for (int m = 0; m < 3; ++m) {
#pragma unroll
        for (int j = 0; j < 4; ++j) acc[j] = make_float4(0.f, 0.f, 0.f, 0.f);
        mmP(acc, xs, wl, wreg, m < 2 ? Ws[m + 1] : nullptr, nullptr, tn, tc);
#pragma unroll
        for (int j = 0; j < 4; ++j) {
            int node = i0 + tn * 4 + j;
            if (node < N) st4(big + (size_t)node * 384 + m * 128 + tc * 4, acc[j]);
        }
    }
}

// ---------------- GAT scores (float4 gathers): exp + segment denominator ----------------
__global__ __launch_bounds__(256) void k_gat_smB(const float* __restrict__ big,
                                                 const int* __restrict__ ei, int E,
                                                 float* __restrict__ scores,
                                                 float* __restrict__ sm) {
    long long t = (long long)blockIdx.x * 256 + threadIdx.x;
    if (t >= (long long)E * 8) return;
    int e = (int)(t >> 3), h = (int)(t & 7);
    int row = ei[e], col = ei[E + e];
    const float4* q = (const float4*)(big + (size_t)row * 384 + h * 16);
    const float4* kk = (const float4*)(big + (size_t)col * 384 + 128 + h * 16);
    float s = 0.f;
#pragma unroll
    for (int d = 0; d < 4; ++d) {
        float4 a = q[d], b = kk[d];
        s += a.x * b.x + a.y * b.y + a.z * b.z + a.w * b.w;
    }
    s *= 0.25f;
    s = s > 0.f ? s : 0.2f * s;
    float ex = expf(s);
    scores[t] = ex;
    atomicAdd(&sm[(size_t)col * 8 + h], ex);
}

// ------- GAT weighted-V, sorted segments: one wave per col, float2 lanes -------
__global__ __launch_bounds__(256) void k_wvS2(const float* __restrict__ big,
                                              const float* __restrict__ scores,
                                              const float* __restrict__ sm,
                                              const int* __restrict__ srow,
                                              const int* __restrict__ sedge,
                                              const int* __restrict__ offA,
                                              float* __restrict__ agg, int N) {
    int l = threadIdx.x & 63;
    int col = blockIdx.x * 4 + (threadIdx.x >> 6);
    if (col >= N) return;
    int h = l >> 3;
    float sv = sm[(size_t)col * 8 + h];
    float ism = sv != 0.f ? 1.f / sv : 0.f;
    float ax = 0.f, ay = 0.f;
    int p = offA[col], pe = offA[col + 1];
    for (; p + 2 <= pe; p += 2) {
        int e0 = sedge[p], r0 = srow[p], e1 = sedge[p + 1], r1 = srow[p + 1];
        float pr0 = scores[(size_t)e0 * 8 + h] * ism;
        float pr1 = scores[(size_t)e1 * 8 + h] * ism;
        float2 v0 = ld2(big + (size_t)r0 * 384 + 256 + 2 * l);
        float2 v1 = ld2(big + (size_t)r1 * 384 + 256 + 2 * l);
        ax = fmaf(pr0, v0.x, ax); ay = fmaf(pr0, v0.y, ay);
        ax = fmaf(pr1, v1.x, ax); ay = fmaf(pr1, v1.y, ay);
    }
    for (; p < pe; ++p) {
        int e = sedge[p], r = srow[p];
        float pr = scores[(size_t)e * 8 + h] * ism;
        float2 v = ld2(big + (size_t)r * 384 + 256 + 2 * l);
        ax = fmaf(pr, v.x, ax); ay = fmaf(pr, v.y, ay);
    }
    st2(agg + (size_t)col * 128 + 2 * l, make_float2(ax, ay));
}

// ---- GAT epilogue + fusion fold (pipelined) ----
__global__ __launch_bounds__(256) void k_ep_gatT(const float* __restrict__ x,
                                                 const float* __restrict__ agg,
                                                 const float* __restrict__ Wo,
                                                 const float* __restrict__ bo,
                                                 const float* __restrict__ g,
                                                 const float* __restrict__ b,
                                                 const float* __restrict__ fusW,
                                                 const float* __restrict__ fus_b,
                                                 float* __restrict__ fused, int N) {
    __shared__ float xs[32 * 128];
    __shared__ float wl[128 * 128];
    int t = threadIdx.x, tn = t >> 5, tc = t & 31;
    int i0 = blockIdx.x * 32;
    stage32(xs, agg, i0, N);
    float4 wreg[16];
    wpre(wreg, Wo);
    float4 acc[4];
    float4 bo4 = ld4(bo + tc * 4);
#pragma unroll
    for (int j = 0; j < 4; ++j) acc[j] = bo4;
    mmP(acc, xs, wl, wreg, fusW, nullptr, tn, tc);
    float4 o[4];
#pragma unroll
    for (int j = 0; j < 4; ++j) {
        int node = i0 + tn * 4 + j; if (node >= N) node = N - 1;
        float4 xr = ld4(x + (size_t)node * 128 + tc * 4);
        float4 v = make_float4(acc[j].x + xr.x, acc[j].y + xr.y,
                               acc[j].z + xr.z, acc[j].w + xr.w);
        o[j] = lnrow(v, g, b, tc);
    }
    float4 fb4 = ld4(fus_b + tc * 4);
#pragma unroll
    for (int j = 0; j < 4; ++j) acc[j] = fb4;
    mmP(acc, xs, wl, wreg, nullptr, o, tn, tc);
#pragma unroll
    for (int j = 0; j < 4; ++j) {
        int node = i0 + tn * 4 + j;
        if (node < N) st4(fused + (size_t)node * 128 + tc * 4, acc[j]);
    }
}

// ---------------- per-type transform (pipelined when tile-uniform type) ----------------
__global__ __launch_bounds__(256) void k_hgcnT(const float* __restrict__ x,
                                               const int* __restrict__ nt,
                                               const int* __restrict__ perm,
                                               const float* __restrict__ Wt,
                                               const float* __restrict__ bt,
                                               float* __restrict__ h_gcn, int N) {
    __shared__ float xs[32 * 128];
    __shared__ float wl[128 * 128];
    int t = threadIdx.x, tn = t >> 5, tc = t & 31;
    int i0 = blockIdx.x * 32;
    // stage via perm
#pragma unroll
    for (int ii = 0; ii < 4; ++ii) {
        int idx = t + ii * 256;
        int r = idx >> 5, c = idx & 31;
        int q = i0 + r; if (q >= N) q = N - 1;
        int node = perm[q];
        st4(xs + r * 128 + c * 4, ld4(x + (size_t)node * 128 + c * 4));
    }
    int qa = i0; if (qa >= N) qa = N - 1;
    int qb = i0 + 31; if (qb >= N) qb = N - 1;
    int t0 = nt[perm[qa]]; t0 = (t0 < 0 || t0 > 5) ? 0 : t0;
    int t1 = nt[perm[qb]]; t1 = (t1 < 0 || t1 > 5) ? 0 : t1;
    float4 acc[4];
    if (t0 == t1) {
        float4 wreg[16];
        wpre(wreg, Wt + (size_t)t0 * 16384);
#pragma unroll
        for (int j = 0; j < 4; ++j) acc[j] = ld4(bt + t0 * 128 + tc * 4);
        mmP(acc, xs, wl, wreg, nullptr, nullptr, tn, tc);
    } else {
        __syncthreads();  // xs visible (boundary block: whole block takes this path)
#pragma unroll
        for (int j = 0; j < 4; ++j) {
            int q = i0 + tn * 4 + j; if (q >= N) q = N - 1;
            int tt = nt[perm[q]]; tt = (tt < 0 || tt > 5) ? 0 : tt;
            const float* W = Wt + (size_t)tt * 16384;
            float4 a = ld4(bt + tt * 128 + tc * 4);
#pragma unroll 2
            for (int k4 = 0; k4 < 32; ++k4) {
                float4 xv = ld4(xs + (tn * 4 + j) * 128 + k4 * 4);
                float4 w0 = ld4(W + (size_t)(k4 * 4 + 0) * 128 + tc * 4);
                float4 w1 = ld4(W + (size_t)(k4 * 4 + 1) * 128 + tc * 4);
                float4 w2 = ld4(W + (size_t)(k4 * 4 + 2) * 128 + tc * 4);
                float4 w3 = ld4(W + (size_t)(k4 * 4 + 3) * 128 + tc * 4);
                fma4(a, xv.x, w0); fma4(a, xv.y, w1);
                fma4(a, xv.z, w2); fma4(a, xv.w, w3);
            }
            acc[j] = a;
        }
    }
#pragma unroll
    for (int j = 0; j < 4; ++j) {
        int q = i0 + tn * 4 + j;
        if (q < N) st4(h_gcn + (size_t)perm[q] * 128 + tc * 4, acc[j]);
    }
}

// ------- layer-1 precompute (pipelined): Pa = h@W1[0:128], Pb = h@W1[128:256] + b1 -------
__global__ __launch_bounds__(256) void k_preT(const float* __restrict__ h,
                                              const float* __restrict__ emb,
                                              const int* __restrict__ tpos,
                                              const float* __restrict__ W1,
                                              const float* __restrict__ b1,
                                              float* __restrict__ Pa,
                                              float* __restrict__ Pb, int N, int mode) {
    __shared__ float xs[32 * 128];
    __shared__ float wl[128 * 128];
    int t = threadIdx.x, tn = t >> 5, tc = t & 31;
    int i0 = blockIdx.x * 32;
#pragma unroll
    for (int ii = 0; ii < 4; ++ii) {
        int idx = t + ii * 256;
        int r = idx >> 5, c = idx & 31;
        int node = i0 + r; if (node >= N) node = N - 1;
        float4 v = ld4(h + (size_t)node * 128 + c * 4);
        if (mode) {
            int tp = tpos[node]; tp = tp < 0 ? 0 : (tp > 49 ? 49 : tp);
            float4 e = ld4(emb + tp * 128 + c * 4);
            v.x += e.x; v.y += e.y; v.z += e.z; v.w += e.w;
        }
        st4(xs + r * 128 + c * 4, v);
    }
    float4 wreg[16];
    wpre(wreg, W1);
    float4 acc[4];
#pragma unroll
    for (int j = 0; j < 4; ++j) acc[j] = make_float4(0.f, 0.f, 0.f, 0.f);
    mmP(acc, xs, wl, wreg, W1 + (size_t)128 * 128, nullptr, tn, tc);
#pragma unroll
    for (int j = 0; j < 4; ++j) {
        int node = i0 + tn * 4 + j;
        if (node < N) st4(Pa + (size_t)node * 128 + tc * 4, acc[j]);
    }
    float4 b14 = ld4(b1 + tc * 4);
#pragma unroll
    for (int j = 0; j < 4; ++j) acc[j] = b14;
    mmP(acc, xs, wl, wreg, nullptr, nullptr, tn, tc);
#pragma unroll
    for (int j = 0; j < 4; ++j) {
        int node = i0 + tn * 4 + j;
        if (node < N) st4(Pb + (size_t)node * 128 + tc * 4, acc[j]);
    }
}

// ------- relu-sum over sorted segment: s[col] = sum_e relu(Pa[row_e]+Pb[col]) -------
__global__ __launch_bounds__(256) void k_rsum2(const float* __restrict__ Pa,
                                               const float* __restrict__ Pb,
                                               const int* __restrict__ srow,
                                               const int* __restrict__ offA,
                                               float* __restrict__ s, int N) {
    int l = threadIdx.x & 63;
    int col = blockIdx.x * 4 + (threadIdx.x >> 6);
    if (col >= N) return;
    float2 pb = ld2(Pb + (size_t)col * 128 + 2 * l);
    float ax = 0.f, ay = 0.f;
    int p = offA[col], pe = offA[col + 1];
    for (; p + 4 <= pe; p += 4) {
        int r0 = srow[p], r1 = srow[p + 1], r2 = srow[p + 2], r3 = srow[p + 3];
        float2 a0 = ld2(Pa + (size_t)r0 * 128 + 2 * l);
        float2 a1 = ld2(Pa + (size_t)r1 * 128 + 2 * l);
        float2 a2 = ld2(Pa + (size_t)r2 * 128 + 2 * l);
        float2 a3 = ld2(Pa + (size_t)r3 * 128 + 2 * l);
        ax += fmaxf(a0.x + pb.x, 0.f) + fmaxf(a1.x + pb.x, 0.f)
            + fmaxf(a2.x + pb.x, 0.f) + fmaxf(a3.x + pb.x, 0.f);
        ay += fmaxf(a0.y + pb.y, 0.f) + fmaxf(a1.y + pb.y, 0.f)
            + fmaxf(a2.y + pb.y, 0.f) + fmaxf(a3.y + pb.y, 0.f);
    }
    for (; p < pe; ++p) {
        int r = srow[p];
        float2 a = ld2(Pa + (size_t)r * 128 + 2 * l);
        ax += fmaxf(a.x + pb.x, 0.f);
        ay += fmaxf(a.y + pb.y, 0.f);
    }
    st2(s + (size_t)col * 128 + 2 * l, make_float2(ax, ay));
}

// ---- GCN epilogue + W2 fold + fusion fold (5 pipelined matmuls) ----
__global__ __launch_bounds__(256) void k_ep_gcnT(const float* __restrict__ x,
                                                 const float* __restrict__ h_gcn,
                                                 const float* __restrict__ s,
                                                 const int* __restrict__ offA,
                                                 const float* __restrict__ W2,
                                                 const float* __restrict__ b2,
                                                 const float* __restrict__ aW1,
                                                 const float* __restrict__ ab1,
                                                 const float* __restrict__ aW2,
                                                 const float* __restrict__ ab2,
                                                 const float* __restrict__ Wo,
                                                 const float* __restrict__ bo,
                                                 const float* __restrict__ g,
                                                 const float* __restrict__ b,
                                                 const float* __restrict__ fusW,
                                                 float* __restrict__ fused, int N) {
    __shared__ float xs[32 * 128];
    __shared__ float wl[128 * 128];
    int t = threadIdx.x, tn = t >> 5, tc = t & 31;
    int i0 = blockIdx.x * 32;
    int node[4];
#pragma unroll
    for (int j = 0; j < 4; ++j) {
        node[j] = i0 + tn * 4 + j; if (node[j] >= N) node[j] = N - 1;
    }
    stage32(xs, s, i0, N);
    float4 wreg[16];
    wpre(wreg, W2);
    // t1 = s@W2 + deg*b2
    float4 t1[4];
    float4 b24 = ld4(b2 + tc * 4);
#pragma unroll
    for (int j = 0; j < 4; ++j) {
        float deg = (float)(offA[node[j] + 1] - offA[node[j]]);
        t1[j] = make_float4(deg * b24.x, deg * b24.y, deg * b24.z, deg * b24.w);
    }
    mmP(t1, xs, wl, wreg, aW1, nullptr, tn, tc);
    // u = relu(t1@aW1 + ab1)
    float4 u[4];
    float4 a14 = ld4(ab1 + tc * 4);
#pragma unroll
    for (int j = 0; j < 4; ++j) u[j] = a14;
    mmP(u, xs, wl, wreg, aW2, t1, tn, tc);
#pragma unroll
    for (int j = 0; j < 4; ++j) {
        u[j].x = fmaxf(u[j].x, 0.f); u[j].y = fmaxf(u[j].y, 0.f);
        u[j].z = fmaxf(u[j].z, 0.f); u[j].w = fmaxf(u[j].w, 0.f);
    }
    // z3 = u@aW2 + ab2 + h_gcn
    float4 z3[4];
    float4 a24 = ld4(ab2 + tc * 4);
#pragma unroll
    for (int j = 0; j < 4; ++j) z3[j] = a24;
    mmP(z3, xs, wl, wreg, Wo, u, tn, tc);
#pragma unroll
    for (int j = 0; j < 4; ++j) {
        float4 hg = ld4(h_gcn + (size_t)node[j] * 128 + tc * 4);
        z3[j].x += hg.x; z3[j].y += hg.y; z3[j].z += hg.z; z3[j].w += hg.w;
    }
    // d = z3@Wo + bo; o = LN(d + x)
    float4 d[4];
    float4 bo4 = ld4(bo + tc * 4);
#pragma unroll
    for (int j = 0; j < 4; ++j) d[j] = bo4;
    mmP(d, xs, wl, wreg, fusW + (size_t)128 * 128, z3, tn, tc);
    float4 o[4];
#pragma unroll
    for (int j = 0; j < 4; ++j) {
        float4 xr = ld4(x + (size_t)node[j] * 128 + tc * 4);
        float4 v = make_float4(d[j].x + xr.x, d[j].y + xr.y,
                               d[j].z + xr.z, d[j].w + xr.w);
        o[j] = lnrow(v, g, b, tc);
    }
    // fused += o @ fusW[128:256]
    float4 f[4];
#pragma unroll
    for (int j = 0; j < 4; ++j) f[j] = ld4(fused + (size_t)node[j] * 128 + tc * 4);
    mmP(f, xs, wl, wreg, nullptr, o, tn, tc);
#pragma unroll
    for (int j = 0; j < 4; ++j) {
        int q = i0 + tn * 4 + j;
        if (q < N) st4(fused + (size_t)q * 128 + tc * 4, f[j]);
    }
}

// ---- temporal epilogue + W2 fold + fusion fold + FINAL LN -> out (pipelined) ----
__global__ __launch_bounds__(256) void k_ep_tmpT(const float* __restrict__ x,
                                                 const float* __restrict__ emb,
                                                 const int* __restrict__ tpos,
                                                 const float* __restrict__ s,
                                                 const int* __restrict__ offA,
                                                 const float* __restrict__ W2,
                                                 const float* __restrict__ b2,
                                                 const float* __restrict__ Wo,
                                                 const float* __restrict__ bo,
                                                 const float* __restrict__ g,
                                                 const float* __restrict__ b,
                                                 const float* __restrict__ fusW,
                                                 const float* __restrict__ fused,
                                                 const float* __restrict__ fg,
                                                 const float* __restrict__ fbe,
                                                 float* __restrict__ out, int N) {
    __shared__ float xs[32 * 128];
    __shared__ float wl[128 * 128];
    int t = threadIdx.x, tn = t >> 5, tc = t & 31;
    int i0 = blockIdx.x * 32;
    int node[4];
#pragma unroll
    for (int j = 0; j < 4; ++j) {
        node[j] = i0 + tn * 4 + j; if (node[j] >= N) node[j] = N - 1;
    }
    stage32(xs, s, i0, N);
    float4 wreg[16];
    wpre(wreg, W2);
    // t1 = s@W2 + deg*b2
    float4 t1[4];
    float4 b24 = ld4(b2 + tc * 4);
#pragma unroll
    for (int j = 0; j < 4; ++j) {
        float deg = (float)(offA[node[j] + 1] - offA[node[j]]);
        t1[j] = make_float4(deg * b24.x, deg * b24.y, deg * b24.z, deg * b24.w);
    }
    mmP(t1, xs, wl, wreg, Wo, nullptr, tn, tc);
    // z = t1 + x + emb[tpos]
#pragma unroll
    for (int j = 0; j < 4; ++j) {
        int tp = tpos[node[j]]; tp = tp < 0 ? 0 : (tp > 49 ? 49 : tp);
        float4 xr = ld4(x + (size_t)node[j] * 128 + tc * 4);
        float4 e = ld4(emb + tp * 128 + tc * 4);
        t1[j].x += xr.x + e.x; t1[j].y += xr.y + e.y;
        t1[j].z += xr.z + e.z; t1[j].w += xr.w + e.w;
    }
    // o = LN(z@Wo + bo)
    float4 d[4];
    float4 bo4 = ld4(bo + tc * 4);
#pragma unroll
    for (int j = 0; j < 4; ++j) d[j] = bo4;
    mmP(d, xs, wl, wreg, fusW + (size_t)256 * 128, t1, tn, tc);
    float4 o[4];
#pragma unroll
    for (int j = 0; j < 4; ++j) o[j] = lnrow(d[j], g, b, tc);
    // fused += o @ fusW[256:384]; out = LN_final(fused)
    float4 f[4];
#pragma unroll
    for (int j = 0; j < 4; ++j) f[j] = ld4(fused + (size_t)node[j] * 128 + tc * 4);
    mmP(f, xs, wl, wreg, nullptr, o, tn, tc);
#pragma unroll
    for (int j = 0; j < 4; ++j) {
        float4 res = lnrow(f[j], fg, fbe, tc);
        int q = i0 + tn * 4 + j;
        if (q < N) st4(out + (size_t)q * 128 + tc * 4, res);
    }
}

extern "C" void kernel_launch(void* const* d_in, const int* in_sizes, int n_in, void* d_out,
                              int out_size, void* d_ws, size_t ws_size, hipStream_t stream) {
    (void)n_in; (void)out_size; (void)ws_size;
    const float* x = (const float*)d_in[0];
    const float* gat_Wq = (const float*)d_in[4];
    const float* gat_Wk = (const float*)d_in[5];
    const float* gat_Wv = (const float*)d_in[6];
    const float* gat_Wo = (const float*)d_in[7];
    const float* gat_bo = (const float*)d_in[8];
    const float* gat_g = (const float*)d_in[9];
    const float* gat_b = (const float*)d_in[10];
    const float* gcn_Wt = (const float*)d_in[11];
    const float* gcn_bt = (const float*)d_in[12];
    const float* gcn_mW1 = (const float*)d_in[13];
    const float* gcn_mb1 = (const float*)d_in[14];
    const float* gcn_mW2 = (const float*)d_in[15];
    const float* gcn_mb2 = (const float*)d_in[16];
    const float* gcn_aW1 = (const float*)d_in[17];
    const float* gcn_ab1 = (const float*)d_in[18];
    const float* gcn_aW2 = (const float*)d_in[19];
    const float* gcn_ab2 = (const float*)d_in[20];
    const float* gcn_Wo = (const float*)d_in[21];
    const float* gcn_bo = (const float*)d_in[22];
    const float* gcn_g = (const float*)d_in[23];
    const float* gcn_b = (const float*)d_in[24];
    const float* tmp_emb = (const float*)d_in[25];
    const float* tmp_W1 = (const float*)d_in[26];
    const float* tmp_b1 = (const float*)d_in[27];
    const float* tmp_W2 = (const float*)d_in[28];
    const float* tmp_b2 = (const float*)d_in[29];
    const float* tmp_Wo = (const float*)d_in[30];
    const float* tmp_bo = (const float*)d_in[31];
    const float* tmp_g = (const float*)d_in[32];
    const float* tmp_b = (const float*)d_in[33];
    const float* fus_W = (const float*)d_in[34];
    const float* fus_b = (const float*)d_in[35];
    const float* fus_g = (const float*)d_in[36];
    const float* fus_be = (const float*)d_in[37];

    int N = in_sizes[0] / 128;
    int E = in_sizes[1] / 2;

    // ---- workspace layout (floats) ----
    float* ws = (float*)d_ws;
    float* big = ws;                          // [0,384N): QKV during GAT phase
    float* fused = ws;                        // [0,128N): alias after QKV dead
    float* h_gcn = ws + (size_t)128 * N;      // [128N,256N)
    float* Pa = ws + (size_t)256 * N;         // [256N,384N)
    float* Pb = ws + (size_t)384 * N;         // [384N,512N)
    float* agg = ws + (size_t)512 * N;        // [512N,640N): GAT agg / relu-sum s
    float* sm = ws + (size_t)640 * N;         // [640N,648N)
    u32* flags = (u32*)(ws + (size_t)648 * N);
    int* ei32 = (int*)(flags + 16);
    int* nt32 = ei32 + (size_t)2 * E;
    int* tp32 = nt32 + N;
    float* scores = (float*)(tp32 + N);       // E*8 floats
    int* offA = (int*)(scores + (size_t)8 * E);  // N+1
    int* cur = offA + (N + 1);                   // N
    int* srow = cur + N;                         // E
    int* sedge = srow + E;                       // E
    int* tcnt = sedge + E;                       // 6
    int* toff = tcnt + 6;                        // 7
    int* tcur = toff + 7;                        // 6
    int* perm = cur;                             // alias: cur dead after col-scatter

    // ---- index canonicalization ----
    k_detect13<<<1, 64, 0, stream>>>((const u32*)d_in[1], (const u32*)d_in[2],
                                     (const u32*)d_in[3], flags);
    long long nEI = (long long)2 * E;
    k_cvt13<<<(int)((nEI + 255) / 256), 256, 0, stream>>>(d_in[1], ei32, nEI, flags, 0);
    k_cvt13<<<(N + 255) / 256, 256, 0, stream>>>(d_in[2], nt32, N, flags, 1);
    k_cvt13<<<(N + 255) / 256, 256, 0, stream>>>(d_in[3], tp32, N, flags, 2);

    int gE = (E + 255) / 256;
    int gN = (N + 255) / 256;
    int gT = (N + 31) / 32;   // tiled kernels: 32 nodes per 256-thread block
    int gC = (N + 3) / 4;     // 4 cols (1 wave each) per 256-thread block
    int gE8 = (int)(((long long)E * 8 + 255) / 256);

    // ---- counting sort of edges by col ----
    kz_i<<<gN, 256, 0, stream>>>(cur, N);
    k_hist<<<gE, 256, 0, stream>>>(ei32, E, cur);
    k_scan<<<1, 1024, 0, stream>>>(cur, offA, N);
    kz_i<<<gN, 256, 0, stream>>>(cur, N);
    k_scatter<<<gE, 256, 0, stream>>>(ei32, E, offA, cur, srow, sedge);

    // ---- counting sort of nodes by type (perm aliases cur: col-scatter done) ----
    kz_i<<<1, 32, 0, stream>>>(tcnt, 19);
    k_thist<<<gN, 256, 0, stream>>>(nt32, N, tcnt);
    k_tscan<<<1, 64, 0, stream>>>(tcnt, toff);
    k_tscatter<<<gN, 256, 0, stream>>>(nt32, N, toff, tcur, perm);

    // ===== GAT branch =====
    kz13<<<(int)(((long long)8 * N + 255) / 256), 256, 0, stream>>>(sm, (long long)8 * N);
    k_qkvT<<<gT, 256, 0, stream>>>(x, gat_Wq, gat_Wk, gat_Wv, big, N);
    k_gat_smB<<<gE8, 256, 0, stream>>>(big, ei32, E, scores, sm);
    k_wvS2<<<gC, 256, 0, stream>>>(big, scores, sm, srow, sedge, offA, agg, N);
    k_ep_gatT<<<gT, 256, 0, stream>>>(x, agg, gat_Wo, gat_bo, gat_g, gat_b,
                                      fus_W, fus_b, fused, N);   // QKV dead after this

    // ===== GCN branch =====
    k_hgcnT<<<gT, 256, 0, stream>>>(x, nt32, perm, gcn_Wt, gcn_bt, h_gcn, N);
    k_preT<<<gT, 256, 0, stream>>>(h_gcn, nullptr, nullptr, gcn_mW1, gcn_mb1, Pa, Pb, N, 0);
    k_rsum2<<<gC, 256, 0, stream>>>(Pa, Pb, srow, offA, agg, N);
    k_ep_gcnT<<<gT, 256, 0, stream>>>(x, h_gcn, agg, offA, gcn_mW2, gcn_mb2,
                                      gcn_aW1, gcn_ab1, gcn_aW2, gcn_ab2,
                                      gcn_Wo, gcn_bo, gcn_g, gcn_b, fus_W, fused, N);

    // ===== temporal branch =====
    k_preT<<<gT, 256, 0, stream>>>(x, tmp_emb, tp32, tmp_W1, tmp_b1, Pa, Pb, N, 1);
    k_rsum2<<<gC, 256, 0, stream>>>(Pa, Pb, srow, offA, agg, N);
    k_ep_tmpT<<<gT, 256, 0, stream>>>(x, tmp_emb, tp32, agg, offA, tmp_W2, tmp_b2,
                                      tmp_Wo, tmp_bo, tmp_g, tmp_b, fus_W, fused,
                                      fus_g, fus_be, (float*)d_out, N);
}

// Round 9
// 475.759 us; speedup vs baseline: 1.1526x; 1.1526x over previous
//
#include <hip/hip_runtime.h>

using u32 = unsigned int;
using s64 = long long;

// -------- int width detection --------
__global__ __launch_bounds__(64) void k_detect13(const u32* __restrict__ ei,
                                                 const u32* __restrict__ nt,
                                                 const u32* __restrict__ tp,
                                                 u32* __restrict__ flags) {
    if (blockIdx.x != 0 || threadIdx.x != 0) return;
    bool e64 = true, n64 = true, t64 = true;
    for (int k = 0; k < 64; ++k) {
        if (ei[2 * k + 1] != 0u) e64 = false;
        if (nt[2 * k + 1] != 0u) n64 = false;
        if (tp[2 * k + 1] != 0u) t64 = false;
    }
    flags[0] = e64 ? 1u : 0u;
    flags[1] = n64 ? 1u : 0u;
    flags[2] = t64 ? 1u : 0u;
}

__global__ __launch_bounds__(256) void k_cvt13(const void* __restrict__ src,
                                               int* __restrict__ dst, long long n,
                                               const u32* __restrict__ flags, int fidx) {
    long long i = (long long)blockIdx.x * 256 + threadIdx.x;
    if (i >= n) return;
    dst[i] = flags[fidx] ? (int)((const s64*)src)[i] : ((const int*)src)[i];
}

__global__ __launch_bounds__(256) void kz13(float* __restrict__ p, long long n) {
    long long i = (long long)blockIdx.x * 256 + threadIdx.x;
    if (i < n) p[i] = 0.f;
}
__global__ __launch_bounds__(256) void kz_i(int* __restrict__ p, int n) {
    int i = blockIdx.x * 256 + threadIdx.x;
    if (i < n) p[i] = 0;
}

// ---------------- counting sort of edges by col ----------------
__global__ __launch_bounds__(256) void k_hist(const int* __restrict__ ei, int E,
                                              int* __restrict__ cnt) {
    int e = blockIdx.x * 256 + threadIdx.x;
    if (e < E) atomicAdd(&cnt[ei[E + e]], 1);
}

__global__ __launch_bounds__(1024) void k_scan(const int* __restrict__ cnt,
                                               int* __restrict__ offA, int N) {
    __shared__ int part[1024];
    int t = threadIdx.x;
    int C = (N + 1023) >> 10;
    int beg = t * C, end = beg + C; if (end > N) end = N;
    int s = 0;
    for (int k = beg; k < end; ++k) s += cnt[k];
    part[t] = s; __syncthreads();
    for (int o = 1; o < 1024; o <<= 1) {
        int v = (t >= o) ? part[t - o] : 0;
        __syncthreads();
        part[t] += v;
        __syncthreads();
    }
    int base = (t == 0) ? 0 : part[t - 1];
    for (int k = beg; k < end; ++k) { offA[k] = base; base += cnt[k]; }
    if (t == 1023) offA[N] = part[1023];
}

__global__ __launch_bounds__(256) void k_scatter(const int* __restrict__ ei, int E,
                                                 const int* __restrict__ offA,
                                                 int* __restrict__ cur,
                                                 int* __restrict__ srow,
                                                 int* __restrict__ sedge) {
    int e = blockIdx.x * 256 + threadIdx.x;
    if (e >= E) return;
    int col = ei[E + e];
    int p = offA[col] + atomicAdd(&cur[col], 1);
    srow[p] = ei[e];
    sedge[p] = e;
}

// ---------------- counting sort of nodes by type ----------------
__global__ __launch_bounds__(256) void k_thist(const int* __restrict__ nt, int N,
                                               int* __restrict__ tcnt) {
    __shared__ int lc[6];
    if (threadIdx.x < 6) lc[threadIdx.x] = 0;
    __syncthreads();
    int i = blockIdx.x * 256 + threadIdx.x;
    if (i < N) {
        int t = nt[i]; t = (t < 0 || t > 5) ? 0 : t;
        atomicAdd(&lc[t], 1);
    }
    __syncthreads();
    if (threadIdx.x < 6 && lc[threadIdx.x] > 0) atomicAdd(&tcnt[threadIdx.x], lc[threadIdx.x]);
}

__global__ __launch_bounds__(64) void k_tscan(const int* __restrict__ tcnt,
                                              int* __restrict__ toff) {
    if (threadIdx.x != 0 || blockIdx.x != 0) return;
    int s = 0;
    for (int t = 0; t < 6; ++t) { toff[t] = s; s += tcnt[t]; }
    toff[6] = s;
}

__global__ __launch_bounds__(256) void k_tscatter(const int* __restrict__ nt, int N,
                                                  const int* __restrict__ toff,
                                                  int* __restrict__ tcur,
                                                  int* __restrict__ perm) {
    __shared__ int lc[6], gb[6];
    if (threadIdx.x < 6) lc[threadIdx.x] = 0;
    __syncthreads();
    int i = blockIdx.x * 256 + threadIdx.x;
    int t = 0, lr = 0;
    if (i < N) {
        t = nt[i]; t = (t < 0 || t > 5) ? 0 : t;
        lr = atomicAdd(&lc[t], 1);
    }
    __syncthreads();
    if (threadIdx.x < 6 && lc[threadIdx.x] > 0)
        gb[threadIdx.x] = atomicAdd(&tcur[threadIdx.x], lc[threadIdx.x]);
    __syncthreads();
    if (i < N) perm[toff[t] + gb[t] + lr] = i;
}

__device__ __forceinline__ float2 ld2(const float* p) { return *(const float2*)p; }
__device__ __forceinline__ void st2(float* p, float2 v) { *(float2*)p = v; }
__device__ __forceinline__ float4 ld4(const float* p) { return *(const float4*)p; }
__device__ __forceinline__ void st4(float* p, float4 v) { *(float4*)p = v; }
__device__ __forceinline__ void fma4(float4& a, float s, float4 w) {
    a.x = fmaf(s, w.x, a.x); a.y = fmaf(s, w.y, a.y);
    a.z = fmaf(s, w.z, a.z); a.w = fmaf(s, w.w, a.w);
}

__device__ __forceinline__ float redrow(float s) {
#pragma unroll
    for (int o = 1; o < 32; o <<= 1) s += __shfl_xor(s, o);
    return s;
}

// ======================= R7-proven staged matmul =======================
// xs 16KB + wl 32KB (half of W) = 48KB -> 3 blocks/CU.

__device__ __forceinline__ void stage_half(float* wl, const float* __restrict__ Wg,
                                           int half) {
    int t = threadIdx.x;
    const float* src = Wg + half * 8192;
#pragma unroll
    for (int i = 0; i < 8; ++i) {
        int idx = (t + i * 256) * 4;
        st4(wl + idx, ld4(src + idx));
    }
}

__device__ __forceinline__ void mm_half(float4 (&acc)[4], const float* xs,
                                        const float* wl, int tn, int tc, int k4base) {
#pragma unroll 2
    for (int k4 = 0; k4 < 16; ++k4) {
        int r = k4 * 4;
        float4 w0 = ld4(wl + (r + 0) * 128 + tc * 4);
        float4 w1 = ld4(wl + (r + 1) * 128 + tc * 4);
        float4 w2 = ld4(wl + (r + 2) * 128 + tc * 4);
        float4 w3 = ld4(wl + (r + 3) * 128 + tc * 4);
#pragma unroll
        for (int j = 0; j < 4; ++j) {
            float4 xv = ld4(xs + (tn * 4 + j) * 128 + (k4base + k4) * 4);
            fma4(acc[j], xv.x, w0); fma4(acc[j], xv.y, w1);
            fma4(acc[j], xv.z, w2); fma4(acc[j], xv.w, w3);
        }
    }
}

__device__ __forceinline__ void mmS(float4 (&acc)[4], const float* xs, float* wl,
                                    const float* __restrict__ Wg, int tn, int tc) {
    __syncthreads();
    stage_half(wl, Wg, 0);
    __syncthreads();
    mm_half(acc, xs, wl, tn, tc, 0);
    __syncthreads();
    stage_half(wl, Wg, 1);
    __syncthreads();
    mm_half(acc, xs, wl, tn, tc, 16);
}

__device__ __forceinline__ void mmG(float4 (&acc)[4], const float* xs,
                                    const float* __restrict__ W, int tn, int tc) {
#pragma unroll 2
    for (int k4 = 0; k4 < 32; ++k4) {
        float4 w0 = ld4(W + (size_t)(k4 * 4 + 0) * 128 + tc * 4);
        float4 w1 = ld4(W + (size_t)(k4 * 4 + 1) * 128 + tc * 4);
        float4 w2 = ld4(W + (size_t)(k4 * 4 + 2) * 128 + tc * 4);
        float4 w3 = ld4(W + (size_t)(k4 * 4 + 3) * 128 + tc * 4);
#pragma unroll
        for (int j = 0; j < 4; ++j) {
            float4 xv = ld4(xs + (tn * 4 + j) * 128 + k4 * 4);
            fma4(acc[j], xv.x, w0); fma4(acc[j], xv.y, w1);
            fma4(acc[j], xv.z, w2); fma4(acc[j], xv.w, w3);
        }
    }
}

__device__ __forceinline__ float4 lnrow(float4 v, const float* g, const float* b, int tc) {
    float m = redrow(v.x + v.y + v.z + v.w) * 0.0078125f;
    float4 d = make_float4(v.x - m, v.y - m, v.z - m, v.w - m);
    float var = redrow(d.x * d.x + d.y * d.y + d.z * d.z + d.w * d.w) * 0.0078125f;
    float r = rsqrtf(var + 1e-5f);
    float4 gg = ld4(g + tc * 4), bb = ld4(b + tc * 4);
    return make_float4(d.x * r * gg.x + bb.x, d.y * r * gg.y + bb.y,
                       d.z * r * gg.z + bb.z, d.w * r * gg.w + bb.w);
}

__device__ __forceinline__ void stage32(float* xs, const float* src, int i0, int N) {
    int t = threadIdx.x;
#pragma unroll
    for (int ii = 0; ii < 4; ++ii) {
        int idx = t + ii * 256;
        int r = idx >> 5, c = idx & 31;
        int node = i0 + r; if (node >= N) node = N - 1;
        st4(xs + r * 128 + c * 4, ld4(src + (size_t)node * 128 + c * 4));
    }
}

__device__ __forceinline__ void xstore(float* xs, const float4 (&v)[4], int tn, int tc) {
#pragma unroll
    for (int j = 0; j < 4; ++j) st4(xs + (tn * 4 + j) * 128 + tc * 4, v[j]);
}

// ============ MEGA1: qkv | hgcn+pre_gcn | pre_tmp ============
__global__ __launch_bounds__(256) void k_mega1(
        const float* __restrict__ x,
        const float* __restrict__ Wq, const float* __restrict__ Wk,
        const float* __restrict__ Wv, float* __restrict__ big,
        const int* __restrict__ nt, const int* __restrict__ perm,
        const float* __restrict__ Wt, const float* __restrict__ bt,
        float* __restrict__ h_gcn,
        const float* __restrict__ mW1, const float* __restrict__ mb1,
        float* __restrict__ Pa_g, float* __restrict__ Pb_g,
        const float* __restrict__ emb, const int* __restrict__ tpos,
        const float* __restrict__ tW1, const float* __restrict__ tb1,
        float* __restrict__ Pa_t, float* __restrict__ Pb_t,
        int N, int gT) {
    __shared__ float xs[32 * 128];
    __shared__ float wl[64 * 128];
    int role = blockIdx.x / gT;
    int bid = blockIdx.x - role * gT;
    int t = threadIdx.x, tn = t >> 5, tc = t & 31;
    int i0 = bid * 32;

    if (role == 0) {
        // -------- QKV --------
        stage32(xs, x, i0, N);
        float4 acc[4];
        const float* Ws[3] = {Wq, Wk, Wv};
#pragma unroll
        for (int m = 0; m < 3; ++m) {
#pragma unroll
            for (int j = 0; j < 4; ++j) acc[j] = make_float4(0.f, 0.f, 0.f, 0.f);
            mmS(acc, xs, wl, Ws[m], tn, tc);
#pragma unroll
            for (int j = 0; j < 4; ++j) {
                int node = i0 + tn * 4 + j;
                if (node < N) st4(big + (size_t)node * 384 + m * 128 + tc * 4, acc[j]);
            }
        }
    } else if (role == 1) {
        // -------- hgcn + pre_gcn chained --------
#pragma unroll
        for (int ii = 0; ii < 4; ++ii) {
            int idx = t + ii * 256;
            int r = idx >> 5, c = idx & 31;
            int q = i0 + r; if (q >= N) q = N - 1;
            int node = perm[q];
            st4(xs + r * 128 + c * 4, ld4(x + (size_t)node * 128 + c * 4));
        }
        int qa = i0; if (qa >= N) qa = N - 1;
        int qb = i0 + 31; if (qb >= N) qb = N - 1;
        int t0 = nt[perm[qa]]; t0 = (t0 < 0 || t0 > 5) ? 0 : t0;
        int t1 = nt[perm[qb]]; t1 = (t1 < 0 || t1 > 5) ? 0 : t1;
        float4 acc[4];
        if (t0 == t1) {
#pragma unroll
            for (int j = 0; j < 4; ++j) acc[j] = ld4(bt + t0 * 128 + tc * 4);
            mmS(acc, xs, wl, Wt + (size_t)t0 * 16384, tn, tc);
        } else {
            __syncthreads();
#pragma unroll
            for (int j = 0; j < 4; ++j) {
                int q = i0 + tn * 4 + j; if (q >= N) q = N - 1;
                int tt = nt[perm[q]]; tt = (tt < 0 || tt > 5) ? 0 : tt;
                const float* W = Wt + (size_t)tt * 16384;
                float4 a = ld4(bt + tt * 128 + tc * 4);
                float4 one[4] = {a, a, a, a};
                (void)one;
                float4 aa[4];
#pragma unroll
                for (int jj = 0; jj < 4; ++jj) aa[jj] = make_float4(0.f, 0.f, 0.f, 0.f);
                // per-node direct matmul
#pragma unroll 2
                for (int k4 = 0; k4 < 32; ++k4) {
                    float4 xv = ld4(xs + (tn * 4 + j) * 128 + k4 * 4);
                    float4 w0 = ld4(W + (size_t)(k4 * 4 + 0) * 128 + tc * 4);
                    float4 w1 = ld4(W + (size_t)(k4 * 4 + 1) * 128 + tc * 4);
                    float4 w2 = ld4(W + (size_t)(k4 * 4 + 2) * 128 + tc * 4);
                    float4 w3 = ld4(W + (size_t)(k4 * 4 + 3) * 128 + tc * 4);
                    fma4(a, xv.x, w0); fma4(a, xv.y, w1);
                    fma4(a, xv.z, w2); fma4(a, xv.w, w3);
                }
                acc[j] = a;
            }
        }
#pragma unroll
        for (int j = 0; j < 4; ++j) {
            int q = i0 + tn * 4 + j;
            if (q < N) st4(h_gcn + (size_t)perm[q] * 128 + tc * 4, acc[j]);
        }
        // chain: xs <- h rows, then Pa/Pb
        __syncthreads();
        xstore(xs, acc, tn, tc);
        float4 pa[4];
#pragma unroll
        for (int j = 0; j < 4; ++j) pa[j] = make_float4(0.f, 0.f, 0.f, 0.f);
        mmS(pa, xs, wl, mW1, tn, tc);
#pragma unroll
        for (int j = 0; j < 4; ++j) {
            int q = i0 + tn * 4 + j;
            if (q < N) st4(Pa_g + (size_t)perm[q] * 128 + tc * 4, pa[j]);
        }
        float4 b14 = ld4(mb1 + tc * 4);
        float4 pb[4];
#pragma unroll
        for (int j = 0; j < 4; ++j) pb[j] = b14;
        mmS(pb, xs, wl, mW1 + (size_t)128 * 128, tn, tc);
#pragma unroll
        for (int j = 0; j < 4; ++j) {
            int q = i0 + tn * 4 + j;
            if (q < N) st4(Pb_g + (size_t)perm[q] * 128 + tc * 4, pb[j]);
        }
    } else {
        // -------- pre_tmp (h = x + emb inline) --------
#pragma unroll
        for (int ii = 0; ii < 4; ++ii) {
            int idx = t + ii * 256;
            int r = idx >> 5, c = idx & 31;
            int node = i0 + r; if (node >= N) node = N - 1;
            float4 v = ld4(x + (size_t)node * 128 + c * 4);
            int tp = tpos[node]; tp = tp < 0 ? 0 : (tp > 49 ? 49 : tp);
            float4 e = ld4(emb + tp * 128 + c * 4);
            v.x += e.x; v.y += e.y; v.z += e.z; v.w += e.w;
            st4(xs + r * 128 + c * 4, v);
        }
        float4 acc[4];
#pragma unroll
        for (int j = 0; j < 4; ++j) acc[j] = make_float4(0.f, 0.f, 0.f, 0.f);
        mmS(acc, xs, wl, tW1, tn, tc);
#pragma unroll
        for (int j = 0; j < 4; ++j) {
            int node = i0 + tn * 4 + j;
            if (node < N) st4(Pa_t + (size_t)node * 128 + tc * 4, acc[j]);
        }
        float4 b14 = ld4(tb1 + tc * 4);
#pragma unroll
        for (int j = 0; j < 4; ++j) acc[j] = b14;
        mmS(acc, xs, wl, tW1 + (size_t)128 * 128, tn, tc);
#pragma unroll
        for (int j = 0; j < 4; ++j) {
            int node = i0 + tn * 4 + j;
            if (node < N) st4(Pb_t + (size_t)node * 128 + tc * 4, acc[j]);
        }
    }
}

// rsum body (s may alias Pb: pb read before s written)
__device__ __forceinline__ void rsum_body(const float* __restrict__ Pa,
                                          const float* __restrict__ Pb,
                                          const int* __restrict__ srow,
                                          const int* __restrict__ offA,
                                          float* __restrict__ s, int N, int cb) {
    int l = threadIdx.x & 63;
    int col = cb * 4 + (threadIdx.x >> 6);
    if (col >= N) return;
    float2 pb = ld2(Pb + (size_t)col * 128 + 2 * l);
    float ax = 0.f, ay = 0.f;
    int p = offA[col], pe = offA[col + 1];
    for (; p + 4 <= pe; p += 4) {
        int r0 = srow[p], r1 = srow[p + 1], r2 = srow[p + 2], r3 = srow[p + 3];
        float2 a0 = ld2(Pa + (size_t)r0 * 128 + 2 * l);
        float2 a1 = ld2(Pa + (size_t)r1 * 128 + 2 * l);
        float2 a2 = ld2(Pa + (size_t)r2 * 128 + 2 * l);
        float2 a3 = ld2(Pa + (size_t)r3 * 128 + 2 * l);
        ax += fmaxf(a0.x + pb.x, 0.f) + fmaxf(a1.x + pb.x, 0.f)
            + fmaxf(a2.x + pb.x, 0.f) + fmaxf(a3.x + pb.x, 0.f);
        ay += fmaxf(a0.y + pb.y, 0.f) + fmaxf(a1.y + pb.y, 0.f)
            + fmaxf(a2.y + pb.y, 0.f) + fmaxf(a3.y + pb.y, 0.f);
    }
    for (; p < pe; ++p) {
        int r = srow[p];
        float2 a = ld2(Pa + (size_t)r * 128 + 2 * l);
        ax += fmaxf(a.x + pb.x, 0.f);
        ay += fmaxf(a.y + pb.y, 0.f);
    }
    st2(s + (size_t)col * 128 + 2 * l, make_float2(ax, ay));
}

// ============ MEGA2: gat_smB | rsum_gcn | rsum_tmp ============
__global__ __launch_bounds__(256) void k_mega2(
        const float* __restrict__ big, const int* __restrict__ ei, int E,
        float* __restrict__ scores, float* __restrict__ sm,
        const float* __restrict__ Pa_g, float* __restrict__ Pb_g,
        const float* __restrict__ Pa_t, float* __restrict__ Pb_t,
        const int* __restrict__ srow, const int* __restrict__ offA,
        int N, int gE8, int gC) {
    int b = blockIdx.x;
    if (b < gE8) {
        long long t = (long long)b * 256 + threadIdx.x;
        if (t >= (long long)E * 8) return;
        int e = (int)(t >> 3), h = (int)(t & 7);
        int row = ei[e], col = ei[E + e];
        const float4* q = (const float4*)(big + (size_t)row * 384 + h * 16);
        const float4* kk = (const float4*)(big + (size_t)col * 384 + 128 + h * 16);
        float s = 0.f;
#pragma unroll
        for (int d = 0; d < 4; ++d) {
            float4 a = q[d], bb = kk[d];
            s += a.x * bb.x + a.y * bb.y + a.z * bb.z + a.w * bb.w;
        }
        s *= 0.25f;
        s = s > 0.f ? s : 0.2f * s;
        float ex = expf(s);
        scores[t] = ex;
        atomicAdd(&sm[(size_t)col * 8 + h], ex);
    } else if (b < gE8 + gC) {
        rsum_body(Pa_g, Pb_g, srow, offA, Pb_g, N, b - gE8);
    } else {
        rsum_body(Pa_t, Pb_t, srow, offA, Pb_t, N, b - gE8 - gC);
    }
}

// ------- GAT weighted-V (sorted segments) -------
__global__ __launch_bounds__(256) void k_wvS2(const float* __restrict__ big,
                                              const float* __restrict__ scores,
                                              const float* __restrict__ sm,
                                              const int* __restrict__ srow,
                                              const int* __restrict__ sedge,
                                              const int* __restrict__ offA,
                                              float* __restrict__ agg, int N) {
    int l = threadIdx.x & 63;
    int col = blockIdx.x * 4 + (threadIdx.x >> 6);
    if (col >= N) return;
    int h = l >> 3;
    float sv = sm[(size_t)col * 8 + h];
    float ism = sv != 0.f ? 1.f / sv : 0.f;
    float ax = 0.f, ay = 0.f;
    int p = offA[col], pe = offA[col + 1];
    for (; p + 2 <= pe; p += 2) {
        int e0 = sedge[p], r0 = srow[p], e1 = sedge[p + 1], r1 = srow[p + 1];
        float pr0 = scores[(size_t)e0 * 8 + h] * ism;
        float pr1 = scores[(size_t)e1 * 8 + h] * ism;
        float2 v0 = ld2(big + (size_t)r0 * 384 + 256 + 2 * l);
        float2 v1 = ld2(big + (size_t)r1 * 384 + 256 + 2 * l);
        ax = fmaf(pr0, v0.x, ax); ay = fmaf(pr0, v0.y, ay);
        ax = fmaf(pr1, v1.x, ax); ay = fmaf(pr1, v1.y, ay);
    }
    for (; p < pe; ++p) {
        int e = sedge[p], r = srow[p];
        float pr = scores[(size_t)e * 8 + h] * ism;
        float2 v = ld2(big + (size_t)r * 384 + 256 + 2 * l);
        ax = fmaf(pr, v.x, ax); ay = fmaf(pr, v.y, ay);
    }
    st2(agg + (size_t)col * 128 + 2 * l, make_float2(ax, ay));
}

// ============ MEGA3: ep_gat | ep_gcn | ep_tmp -> o_* (LN outputs) ============
__global__ __launch_bounds__(256) void k_mega3(
        const float* __restrict__ x,
        const float* __restrict__ agg,
        const float* __restrict__ gWo, const float* __restrict__ gbo,
        const float* __restrict__ gg, const float* __restrict__ gb,
        float* __restrict__ o_gat,
        const float* __restrict__ h_gcn, const float* __restrict__ s_gcn,
        const int* __restrict__ offA,
        const float* __restrict__ W2, const float* __restrict__ b2,
        const float* __restrict__ aW1, const float* __restrict__ ab1,
        const float* __restrict__ aW2, const float* __restrict__ ab2,
        const float* __restrict__ cWo, const float* __restrict__ cbo,
        const float* __restrict__ cg, const float* __restrict__ cb,
        float* __restrict__ o_gcn,
        const float* __restrict__ emb, const int* __restrict__ tpos,
        const float* __restrict__ s_tmp,
        const float* __restrict__ tW2, const float* __restrict__ tb2,
        const float* __restrict__ tWo, const float* __restrict__ tbo,
        const float* __restrict__ tg, const float* __restrict__ tb,
        float* __restrict__ o_tmp,
        int N, int gT) {
    __shared__ float xs[32 * 128];
    __shared__ float wl[64 * 128];
    int role = blockIdx.x / gT;
    int bid = blockIdx.x - role * gT;
    int t = threadIdx.x, tn = t >> 5, tc = t & 31;
    int i0 = bid * 32;
    int node[4];
#pragma unroll
    for (int j = 0; j < 4; ++j) {
        node[j] = i0 + tn * 4 + j; if (node[j] >= N) node[j] = N - 1;
    }

    if (role == 0) {
        // -------- ep_gat: o = LN(agg@Wo + bo + x) --------
        stage32(xs, agg, i0, N);
        float4 acc[4];
        float4 bo4 = ld4(gbo + tc * 4);
#pragma unroll
        for (int j = 0; j < 4; ++j) acc[j] = bo4;
        mmS(acc, xs, wl, gWo, tn, tc);
#pragma unroll
        for (int j = 0; j < 4; ++j) {
            float4 xr = ld4(x + (size_t)node[j] * 128 + tc * 4);
            float4 v = make_float4(acc[j].x + xr.x, acc[j].y + xr.y,
                                   acc[j].z + xr.z, acc[j].w + xr.w);
            float4 o = lnrow(v, gg, gb, tc);
            int q = i0 + tn * 4 + j;
            if (q < N) st4(o_gat + (size_t)q * 128 + tc * 4, o);
        }
    } else if (role == 1) {
        // -------- ep_gcn: 4 matmuls + LN --------
        stage32(xs, s_gcn, i0, N);
        float4 acc[4];
        float4 b24 = ld4(b2 + tc * 4);
#pragma unroll
        for (int j = 0; j < 4; ++j) {
            float deg = (float)(offA[node[j] + 1] - offA[node[j]]);
            acc[j] = make_float4(deg * b24.x, deg * b24.y, deg * b24.z, deg * b24.w);
        }
        mmS(acc, xs, wl, W2, tn, tc);
        __syncthreads();
        xstore(xs, acc, tn, tc);
        float4 u[4];
        float4 a14 = ld4(ab1 + tc * 4);
#pragma unroll
        for (int j = 0; j < 4; ++j) u[j] = a14;
        mmS(u, xs, wl, aW1, tn, tc);
#pragma unroll
        for (int j = 0; j < 4; ++j) {
            u[j].x = fmaxf(u[j].x, 0.f); u[j].y = fmaxf(u[j].y, 0.f);
            u[j].z = fmaxf(u[j].z, 0.f); u[j].w = fmaxf(u[j].w, 0.f);
        }
        __syncthreads();
        xstore(xs, u, tn, tc);
        float4 z3[4];
        float4 a24 = ld4(ab2 + tc * 4);
#pragma unroll
        for (int j = 0; j < 4; ++j) z3[j] = a24;
        mmS(z3, xs, wl, aW2, tn, tc);
#pragma unroll
        for (int j = 0; j < 4; ++j) {
            float4 hg = ld4(h_gcn + (size_t)node[j] * 128 + tc * 4);
            z3[j].x += hg.x; z3[j].y += hg.y; z3[j].z += hg.z; z3[j].w += hg.w;
        }
        __syncthreads();
        xstore(xs, z3, tn, tc);
        float4 d[4];
        float4 bo4 = ld4(cbo + tc * 4);
#pragma unroll
        for (int j = 0; j < 4; ++j) d[j] = bo4;
        mmS(d, xs, wl, cWo, tn, tc);
#pragma unroll
        for (int j = 0; j < 4; ++j) {
            float4 xr = ld4(x + (size_t)node[j] * 128 + tc * 4);
            float4 v = make_float4(d[j].x + xr.x, d[j].y + xr.y,
                                   d[j].z + xr.z, d[j].w + xr.w);
            float4 o = lnrow(v, cg, cb, tc);
            int q = i0 + tn * 4 + j;
            if (q < N) st4(o_gcn + (size_t)q * 128 + tc * 4, o);
        }
    } else {
        // -------- ep_tmp: 2 matmuls + LN --------
        stage32(xs, s_tmp, i0, N);
        float4 acc[4];
        float4 b24 = ld4(tb2 + tc * 4);
#pragma unroll
        for (int j = 0; j < 4; ++j) {
            float deg = (float)(offA[node[j] + 1] - offA[node[j]]);
            acc[j] = make_float4(deg * b24.x, deg * b24.y, deg * b24.z, deg * b24.w);
        }
        mmS(acc, xs, wl, tW2, tn, tc);
#pragma unroll
        for (int j = 0; j < 4; ++j) {
            int tp = tpos[node[j]]; tp = tp < 0 ? 0 : (tp > 49 ? 49 : tp);
            float4 xr = ld4(x + (size_t)node[j] * 128 + tc * 4);
            float4 e = ld4(emb + tp * 128 + tc * 4);
            acc[j].x += xr.x + e.x; acc[j].y += xr.y + e.y;
            acc[j].z += xr.z + e.z; acc[j].w += xr.w + e.w;
        }
        __syncthreads();
        xstore(xs, acc, tn, tc);
        float4 d[4];
        float4 bo4 = ld4(tbo + tc * 4);
#pragma unroll
        for (int j = 0; j < 4; ++j) d[j] = bo4;
        mmS(d, xs, wl, tWo, tn, tc);
#pragma unroll
        for (int j = 0; j < 4; ++j) {
            float4 o = lnrow(d[j], tg, tb, tc);
            int q = i0 + tn * 4 + j;
            if (q < N) st4(o_tmp + (size_t)q * 128 + tc * 4, o);
        }
    }
}

// ============ FINAL: out = LN(fus_b + o_gat@W0 + o_gcn@W1 + o_tmp@W2) ============
__global__ __launch_bounds__(256) void k_final3(
        const float* __restrict__ o_gat, const float* __restrict__ o_gcn,
        const float* __restrict__ o_tmp,
        const float* __restrict__ fusW, const float* __restrict__ fus_b,
        const float* __restrict__ fg, const float* __restrict__ fbe,
        float* __restrict__ out, int N) {
    __shared__ float xs[32 * 128];
    __shared__ float wl[64 * 128];
    int t = threadIdx.x, tn = t >> 5, tc = t & 31;
    int i0 = blockIdx.x * 32;
    stage32(xs, o_gat, i0, N);
    float4 acc[4];
    float4 fb4 = ld4(fus_b + tc * 4);
#pragma unroll
    for (int j = 0; j < 4; ++j) acc[j] = fb4;
    mmS(acc, xs, wl, fusW, tn, tc);
    __syncthreads();
    stage32(xs, o_gcn, i0, N);
    mmS(acc, xs, wl, fusW + (size_t)128 * 128, tn, tc);
    __syncthreads();
    stage32(xs, o_tmp, i0, N);
    mmS(acc, xs, wl, fusW + (size_t)256 * 128, tn, tc);
#pragma unroll
    for (int j = 0; j < 4; ++j) {
        float4 res = lnrow(acc[j], fg, fbe, tc);
        int q = i0 + tn * 4 + j;
        if (q < N) st4(out + (size_t)q * 128 + tc * 4, res);
    }
}

extern "C" void kernel_launch(void* const* d_in, const int* in_sizes, int n_in, void* d_out,
                              int out_size, void* d_ws, size_t ws_size, hipStream_t stream) {
    (void)n_in; (void)out_size; (void)ws_size;
    const float* x = (const float*)d_in[0];
    const float* gat_Wq = (const float*)d_in[4];
    const float* gat_Wk = (const float*)d_in[5];
    const float* gat_Wv = (const float*)d_in[6];
    const float* gat_Wo = (const float*)d_in[7];
    const float* gat_bo = (const float*)d_in[8];
    const float* gat_g = (const float*)d_in[9];
    const float* gat_b = (const float*)d_in[10];
    const float* gcn_Wt = (const float*)d_in[11];
    const float* gcn_bt = (const float*)d_in[12];
    const float* gcn_mW1 = (const float*)d_in[13];
    const float* gcn_mb1 = (const float*)d_in[14];
    const float* gcn_mW2 = (const float*)d_in[15];
    const float* gcn_mb2 = (const float*)d_in[16];
    const float* gcn_aW1 = (const float*)d_in[17];
    const float* gcn_ab1 = (const float*)d_in[18];
    const float* gcn_aW2 = (const float*)d_in[19];
    const float* gcn_ab2 = (const float*)d_in[20];
    const float* gcn_Wo = (const float*)d_in[21];
    const float* gcn_bo = (const float*)d_in[22];
    const float* gcn_g = (const float*)d_in[23];
    const float* gcn_b = (const float*)d_in[24];
    const float* tmp_emb = (const float*)d_in[25];
    const float* tmp_W1 = (const float*)d_in[26];
    const float* tmp_b1 = (const float*)d_in[27];
    const float* tmp_W2 = (const float*)d_in[28];
    const float* tmp_b2 = (const float*)d_in[29];
    const float* tmp_Wo = (const float*)d_in[30];
    const float* tmp_bo = (const float*)d_in[31];
    const float* tmp_g = (const float*)d_in[32];
    const float* tmp_b = (const float*)d_in[33];
    const float* fus_W = (const float*)d_in[34];
    const float* fus_b = (const float*)d_in[35];
    const float* fus_g = (const float*)d_in[36];
    const float* fus_be = (const float*)d_in[37];

    int N = in_sizes[0] / 128;
    int E = in_sizes[1] / 2;

    // ---- workspace layout ----
    float* ws = (float*)d_ws;
    float* big = ws;                          // [0,384N): QKV; o_* after wvS2
    float* o_gat = ws;                        // [0,128N)
    float* o_gcn = ws + (size_t)128 * N;      // [128N,256N)
    float* o_tmp = ws + (size_t)256 * N;      // [256N,384N)
    float* h_gcn = ws + (size_t)384 * N;      // [384N,512N)
    float* Pa_g = ws + (size_t)512 * N;       // [512N,640N); agg aliases after MEGA2
    float* Pb_g = ws + (size_t)640 * N;       // [640N,768N); s_gcn in-place
    float* Pa_t = ws + (size_t)768 * N;       // [768N,896N)
    float* Pb_t = ws + (size_t)896 * N;       // [896N,1024N); s_tmp in-place
    float* sm = ws + (size_t)1024 * N;        // [1024N,1032N)
    float* agg = Pa_g;
    u32* flags = (u32*)(ws + (size_t)1032 * N);
    int* ei32 = (int*)(flags + 16);
    int* nt32 = ei32 + (size_t)2 * E;
    int* tp32 = nt32 + N;
    float* scores = (float*)(tp32 + N);       // 8E
    int* offA = (int*)(scores + (size_t)8 * E);  // N+1
    int* cur = offA + (N + 1);                   // N
    int* srow = cur + N;                         // E
    int* sedge = srow + E;                       // E
    int* tcnt = sedge + E;                       // 6
    int* toff = tcnt + 6;                        // 7
    int* tcur = toff + 7;                        // 6
    int* perm = cur;                             // alias after col-scatter

    // ---- index canonicalization ----
    k_detect13<<<1, 64, 0, stream>>>((const u32*)d_in[1], (const u32*)d_in[2],
                                     (const u32*)d_in[3], flags);
    long long nEI = (long long)2 * E;
    k_cvt13<<<(int)((nEI + 255) / 256), 256, 0, stream>>>(d_in[1], ei32, nEI, flags, 0);
    k_cvt13<<<(N + 255) / 256, 256, 0, stream>>>(d_in[2], nt32, N, flags, 1);
    k_cvt13<<<(N + 255) / 256, 256, 0, stream>>>(d_in[3], tp32, N, flags, 2);

    int gE = (E + 255) / 256;
    int gN = (N + 255) / 256;
    int gT = (N + 31) / 32;
    int gC = (N + 3) / 4;
    int gE8 = (int)(((long long)E * 8 + 255) / 256);

    // ---- counting sort of edges by col ----
    kz_i<<<gN, 256, 0, stream>>>(cur, N);
    k_hist<<<gE, 256, 0, stream>>>(ei32, E, cur);
    k_scan<<<1, 1024, 0, stream>>>(cur, offA, N);
    kz_i<<<gN, 256, 0, stream>>>(cur, N);
    k_scatter<<<gE, 256, 0, stream>>>(ei32, E, offA, cur, srow, sedge);

    // ---- counting sort of nodes by type ----
    kz_i<<<1, 32, 0, stream>>>(tcnt, 19);
    k_thist<<<gN, 256, 0, stream>>>(nt32, N, tcnt);
    k_tscan<<<1, 64, 0, stream>>>(tcnt, toff);
    k_tscatter<<<gN, 256, 0, stream>>>(nt32, N, toff, tcur, perm);

    // ---- sm zero ----
    kz13<<<(int)(((long long)8 * N + 255) / 256), 256, 0, stream>>>(sm, (long long)8 * N);

    // ---- MEGA1: qkv | hgcn+pre_gcn | pre_tmp ----
    k_mega1<<<3 * gT, 256, 0, stream>>>(x, gat_Wq, gat_Wk, gat_Wv, big,
                                        nt32, perm, gcn_Wt, gcn_bt, h_gcn,
                                        gcn_mW1, gcn_mb1, Pa_g, Pb_g,
                                        tmp_emb, tp32, tmp_W1, tmp_b1, Pa_t, Pb_t,
                                        N, gT);

    // ---- MEGA2: gat scores | rsum_gcn | rsum_tmp ----
    k_mega2<<<gE8 + 2 * gC, 256, 0, stream>>>(big, ei32, E, scores, sm,
                                              Pa_g, Pb_g, Pa_t, Pb_t,
                                              srow, offA, N, gE8, gC);

    // ---- GAT weighted-V (agg overwrites Pa_g slot) ----
    k_wvS2<<<gC, 256, 0, stream>>>(big, scores, sm, srow, sedge, offA, agg, N);

    // ---- MEGA3: three epilogues -> o_gat/o_gcn/o_tmp (overwrite big) ----
    k_mega3<<<3 * gT, 256, 0, stream>>>(x, agg, gat_Wo, gat_bo, gat_g, gat_b, o_gat,
                                        h_gcn, Pb_g, offA, gcn_mW2, gcn_mb2,
                                        gcn_aW1, gcn_ab1, gcn_aW2, gcn_ab2,
                                        gcn_Wo, gcn_bo, gcn_g, gcn_b, o_gcn,
                                        tmp_emb, tp32, Pb_t, tmp_W2, tmp_b2,
                                        tmp_Wo, tmp_bo, tmp_g, tmp_b, o_tmp,
                                        N, gT);

    // ---- FINAL: fuse + LN -> out ----
    k_final3<<<gT, 256, 0, stream>>>(o_gat, o_gcn, o_tmp, fus_W, fus_b,
                                     fus_g, fus_be, (float*)d_out, N);
}